// Round 13
// baseline (397.614 us; speedup 1.0000x reference)
//
#include <hip/hip_runtime.h>

#define B 4
#define C 19
#define H 192
#define W 192
#define HW (H * W)
#define NPLANE (B * C)          // 76
// 40 / ln(2): exp(-40*x) == exp2(-THETA_LOG2E*x)
#define THETA_LOG2E 57.70780163555855f

#define CSEGS 8
#define CSR 24                  // rows per segment (column item)
#define NTHR 512

#define IPP 27                  // items per plane per phase: 3 col + 24 row
#define PHITEMS (NPLANE * IPP)  // 2052
#define COMBPP 18               // combine chunks per plane (2048 elems each)
#define TOTAL_ITEMS (3 * PHITEMS + NPLANE * COMBPP)   // 7524
#define NBLOCKS 1024
#define NCTRL 256               // control words zeroed: pop + 3*76 flags (padded)

// bf16 helpers (RNE)
__device__ __forceinline__ unsigned short f2b(float x) {
    unsigned u = __float_as_uint(x);
    u = (u + 0x7FFFu + ((u >> 16) & 1u)) >> 16;
    return (unsigned short)u;
}
__device__ __forceinline__ float b2f(unsigned short h) {
    return __uint_as_float(((unsigned)h) << 16);
}

__global__ void k_zero(unsigned* __restrict__ ctrl) {
    ctrl[threadIdx.x] = 0u;
}

// ---------------- column item: 64 cols x 192 rows, 8 segs x 24 rows ----------------
// MODE 0: f = mask; c==0 also writes dcol = Zu+Su-1.  MODE 1: f = (cs+rs)/(dcol+drow-1)
template<int MODE>
__device__ void col_item(int b, int c, int jt,
                         const float* __restrict__ mask, const float* __restrict__ edge,
                         const unsigned short* __restrict__ csin,
                         const unsigned short* __restrict__ rsin,
                         unsigned short* __restrict__ csout,
                         float* __restrict__ dcol, const float* __restrict__ drow,
                         float* sPf, float* sQf, float* sPb, float* sQb, int t) {
    int jl = t & 63, seg = t >> 6;
    int j = jt * 64 + jl, i0 = seg * CSR;
    int bc = b * C + c;
    const float* ep = edge + ((size_t)b * H + i0) * W + j;
    const size_t fb = ((size_t)bc * H + i0) * W + j;
    const size_t db = ((size_t)b * H + i0) * W + j;

    float dr[CSR + 1], fr[CSR];
    #pragma unroll
    for (int r = 0; r < CSR; ++r) dr[r] = exp2f(-THETA_LOG2E * fmaxf(ep[r * W], 0.f));
    dr[CSR] = (seg < CSEGS - 1) ? exp2f(-THETA_LOG2E * fmaxf(ep[CSR * W], 0.f)) : 0.f;

    if (MODE == 0) {
        #pragma unroll
        for (int r = 0; r < CSR; ++r) fr[r] = mask[fb + r * W];
    } else {
        #pragma unroll
        for (int r = 0; r < CSR; ++r) {
            float rd = 1.f / (dcol[db + r * W] + drow[db + r * W] - 1.f);
            fr[r] = (b2f(csin[fb + r * W]) + b2f(rsin[fb + r * W])) * rd;
        }
    }

    float Pf = 1.f, Qf = 0.f, Pb = 1.f, Qb = 0.f;
    #pragma unroll
    for (int r = 0; r < CSR; ++r) { Qf = Qf * dr[r] + fr[r]; Pf *= dr[r]; }
    #pragma unroll
    for (int r = CSR - 1; r >= 0; --r) { Qb = Qb * dr[r + 1] + fr[r]; Pb *= dr[r + 1]; }
    sPf[seg * 64 + jl] = Pf; sQf[seg * 64 + jl] = Qf;
    sPb[seg * 64 + jl] = Pb; sQb[seg * 64 + jl] = Qb;
    __syncthreads();
    if (seg == 0) {          // inclusive prefix transforms
        float P = sPf[jl], Q = sQf[jl];
        for (int s2 = 1; s2 < CSEGS; ++s2) {
            float Pc = sPf[s2 * 64 + jl], Qc = sQf[s2 * 64 + jl];
            Q = Q * Pc + Qc; P = P * Pc;
            sPf[s2 * 64 + jl] = P; sQf[s2 * 64 + jl] = Q;
        }
    } else if (seg == 1) {   // inclusive suffix transforms
        float P = sPb[(CSEGS - 1) * 64 + jl], Q = sQb[(CSEGS - 1) * 64 + jl];
        for (int s2 = CSEGS - 2; s2 >= 0; --s2) {
            float Pc = sPb[s2 * 64 + jl], Qc = sQb[s2 * 64 + jl];
            Q = Q * Pc + Qc; P = P * Pc;
            sPb[s2 * 64 + jl] = P; sQb[s2 * 64 + jl] = Q;
        }
    }
    __syncthreads();
    float z = (seg > 0) ? sQf[(seg - 1) * 64 + jl] : 0.f;
    float s = (seg < CSEGS - 1) ? sQb[(seg + 1) * 64 + jl] : 0.f;
    float zarr[CSR];
    #pragma unroll
    for (int r = 0; r < CSR; ++r) { z = z * dr[r] + fr[r]; zarr[r] = z; }
    #pragma unroll
    for (int r = CSR - 1; r >= 0; --r) {
        s = s * dr[r + 1] + fr[r];
        csout[fb + r * W] = f2b(zarr[r] + s - fr[r]);    // diagonal counted once
    }

    if (MODE == 0 && c == 0) {
        // unit-f column scan -> dcol = Zu + Su - 1 (fp32)
        float Pf2 = 1.f, Qf2 = 0.f, Pb2 = 1.f, Qb2 = 0.f;
        #pragma unroll
        for (int r = 0; r < CSR; ++r) { Qf2 = Qf2 * dr[r] + 1.f; Pf2 *= dr[r]; }
        #pragma unroll
        for (int r = CSR - 1; r >= 0; --r) { Qb2 = Qb2 * dr[r + 1] + 1.f; Pb2 *= dr[r + 1]; }
        __syncthreads();
        sPf[seg * 64 + jl] = Pf2; sQf[seg * 64 + jl] = Qf2;
        sPb[seg * 64 + jl] = Pb2; sQb[seg * 64 + jl] = Qb2;
        __syncthreads();
        if (seg == 0) {
            float P = sPf[jl], Q = sQf[jl];
            for (int s2 = 1; s2 < CSEGS; ++s2) {
                float Pc = sPf[s2 * 64 + jl], Qc = sQf[s2 * 64 + jl];
                Q = Q * Pc + Qc; P = P * Pc;
                sPf[s2 * 64 + jl] = P; sQf[s2 * 64 + jl] = Q;
            }
        } else if (seg == 1) {
            float P = sPb[(CSEGS - 1) * 64 + jl], Q = sQb[(CSEGS - 1) * 64 + jl];
            for (int s2 = CSEGS - 2; s2 >= 0; --s2) {
                float Pc = sPb[s2 * 64 + jl], Qc = sQb[s2 * 64 + jl];
                Q = Q * Pc + Qc; P = P * Pc;
                sPb[s2 * 64 + jl] = P; sQb[s2 * 64 + jl] = Q;
            }
        }
        __syncthreads();
        float zu = (seg > 0) ? sQf[(seg - 1) * 64 + jl] : 0.f;
        float su = (seg < CSEGS - 1) ? sQb[(seg + 1) * 64 + jl] : 0.f;
        #pragma unroll
        for (int r = 0; r < CSR; ++r) { zu = zu * dr[r] + 1.f; zarr[r] = zu; }
        #pragma unroll
        for (int r = CSR - 1; r >= 0; --r) {
            su = su * dr[r + 1] + 1.f;
            dcol[db + r * W] = zarr[r] + su - 1.f;
        }
    }
}

// ---------------- row item: 8 rows (one per wave), in-register Kogge-Stone ----------------
template<int MODE>
__device__ void row_item(int b, int c, int rblk,
                         const float* __restrict__ mask, const float* __restrict__ edge,
                         const unsigned short* __restrict__ csin,
                         const unsigned short* __restrict__ rsin,
                         unsigned short* __restrict__ rsout,
                         const float* __restrict__ dcol, float* __restrict__ drow, int t) {
    int wave = t >> 6, lane = t & 63;
    int i = rblk * 8 + wave;
    const size_t rb = ((size_t)(b * C + c) * H + i) * W;
    const int db = (b * H + i) * W;
    const int s0 = 3 * lane;

    float e0 = edge[db + s0], e1 = edge[db + s0 + 1], e2 = edge[db + s0 + 2];
    float d0 = exp2f(-THETA_LOG2E * fmaxf(e0, 0.f));
    float d1 = exp2f(-THETA_LOG2E * fmaxf(e1, 0.f));
    float d2 = exp2f(-THETA_LOG2E * fmaxf(e2, 0.f));
    float d3 = 0.f;
    if (lane < 63) {
        float e3 = edge[db + s0 + 3];
        d3 = exp2f(-THETA_LOG2E * fmaxf(e3, 0.f));
    }

    float f0, f1, f2;
    if (MODE == 0) {
        f0 = mask[rb + s0]; f1 = mask[rb + s0 + 1]; f2 = mask[rb + s0 + 2];
    } else {
        float rd0 = 1.f / (dcol[db + s0]     + drow[db + s0]     - 1.f);
        float rd1 = 1.f / (dcol[db + s0 + 1] + drow[db + s0 + 1] - 1.f);
        float rd2 = 1.f / (dcol[db + s0 + 2] + drow[db + s0 + 2] - 1.f);
        f0 = (b2f(csin[rb + s0])     + b2f(rsin[rb + s0]))     * rd0;
        f1 = (b2f(csin[rb + s0 + 1]) + b2f(rsin[rb + s0 + 1])) * rd1;
        f2 = (b2f(csin[rb + s0 + 2]) + b2f(rsin[rb + s0 + 2])) * rd2;
    }

    // forward scan: Z[s] = d[s]*Z[s-1] + f[s]
    float P = d0 * d1 * d2;
    float Q = (f0 * d1 + f1) * d2 + f2;
    #pragma unroll
    for (int off = 1; off < 64; off <<= 1) {
        float Pp = __shfl_up(P, off);
        float Qp = __shfl_up(Q, off);
        if (lane >= off) { Q = Qp * P + Q; P = Pp * P; }
    }
    float zin = __shfl_up(Q, 1);
    if (lane == 0) zin = 0.f;
    float zA = zin * d0 + f0;
    float zB = zA * d1 + f1;
    float zC = zB * d2 + f2;

    // backward scan: Sf[s] = d[s+1]*Sf[s+1] + f[s]
    float Pb = d3 * d2 * d1;
    float Qb = (f2 * d2 + f1) * d1 + f0;
    #pragma unroll
    for (int off = 1; off < 64; off <<= 1) {
        float Pp = __shfl_down(Pb, off);
        float Qp = __shfl_down(Qb, off);
        if (lane < 64 - off) { Qb = Qp * Pb + Qb; Pb = Pp * Pb; }
    }
    float sin_ = __shfl_down(Qb, 1);
    if (lane == 63) sin_ = 0.f;
    float sC = sin_ * d3 + f2;
    float sB = sC * d2 + f1;
    float sA = sB * d1 + f0;

    rsout[rb + s0]     = f2b(zA + sA - 2.f * f0);
    rsout[rb + s0 + 1] = f2b(zB + sB - 2.f * f1);
    rsout[rb + s0 + 2] = f2b(zC + sC - 2.f * f2);

    if (MODE == 0 && c == 0) {
        // unit-f row scan -> drow = Zu + Su - 1 (fp32)
        float Pu = d0 * d1 * d2;
        float Qu = d1 * d2 + d2 + 1.f;
        #pragma unroll
        for (int off = 1; off < 64; off <<= 1) {
            float Pp = __shfl_up(Pu, off);
            float Qp = __shfl_up(Qu, off);
            if (lane >= off) { Qu = Qp * Pu + Qu; Pu = Pp * Pu; }
        }
        float zuin = __shfl_up(Qu, 1);
        if (lane == 0) zuin = 0.f;
        float zuA = zuin * d0 + 1.f;
        float zuB = zuA * d1 + 1.f;
        float zuC = zuB * d2 + 1.f;

        float Pub = d3 * d2 * d1;
        float Qub = d2 * d1 + d1 + 1.f;
        #pragma unroll
        for (int off = 1; off < 64; off <<= 1) {
            float Pp = __shfl_down(Pub, off);
            float Qp = __shfl_down(Qub, off);
            if (lane < 64 - off) { Qub = Qp * Pub + Qub; Pub = Pp * Pub; }
        }
        float suin = __shfl_down(Qub, 1);
        if (lane == 63) suin = 0.f;
        float suC = suin * d3 + 1.f;
        float suB = suC * d2 + 1.f;
        float suA = suB * d1 + 1.f;

        drow[db + s0]     = zuA + suA - 1.f;
        drow[db + s0 + 1] = zuB + suB - 1.f;
        drow[db + s0 + 2] = zuC + suC - 1.f;
    }
}

// ---------------- combine chunk: out = (cs + rs) / (dcol + drow - 1), 2048 elems ----------------
__device__ void comb_item(int p, int chunk,
                          const unsigned short* __restrict__ cs,
                          const unsigned short* __restrict__ rs,
                          const float* __restrict__ dcol, const float* __restrict__ drow,
                          float* __restrict__ out, int t) {
    int b = p / C;
    size_t base  = (size_t)p * HW + chunk * 2048 + t * 4;
    size_t dbase = (size_t)b * HW + chunk * 2048 + t * 4;
    uint2 csu = *(const uint2*)(cs + base);
    uint2 rsu = *(const uint2*)(rs + base);
    float4 dc = *(const float4*)(dcol + dbase);
    float4 dw = *(const float4*)(drow + dbase);
    float4 o;
    o.x = (b2f((unsigned short)(csu.x & 0xffff)) + b2f((unsigned short)(rsu.x & 0xffff))) / (dc.x + dw.x - 1.f);
    o.y = (b2f((unsigned short)(csu.x >> 16))    + b2f((unsigned short)(rsu.x >> 16)))    / (dc.y + dw.y - 1.f);
    o.z = (b2f((unsigned short)(csu.y & 0xffff)) + b2f((unsigned short)(rsu.y & 0xffff))) / (dc.z + dw.z - 1.f);
    o.w = (b2f((unsigned short)(csu.y >> 16))    + b2f((unsigned short)(rsu.y >> 16)))    / (dc.w + dw.w - 1.f);
    *(float4*)(out + base) = o;
}

// wait until *f >= target (called by t==0 only); relaxed spin + final acquire
__device__ __forceinline__ void wait_ge(unsigned* f, unsigned target) {
    while (__hip_atomic_load(f, __ATOMIC_RELAXED, __HIP_MEMORY_SCOPE_AGENT) < target)
        __builtin_amdgcn_s_sleep(2);
    (void)__hip_atomic_load(f, __ATOMIC_ACQUIRE, __HIP_MEMORY_SCOPE_AGENT);
}

// ---------------- persistent pipelined kernel ----------------
__global__ __launch_bounds__(NTHR) void k_pipe(const float* __restrict__ mask,
                                               const float* __restrict__ edge,
                                               float* __restrict__ out,
                                               unsigned* __restrict__ ctrl,
                                               float* __restrict__ dcol, float* __restrict__ drow,
                                               unsigned short* __restrict__ csA,
                                               unsigned short* __restrict__ rsA,
                                               unsigned short* __restrict__ csB,
                                               unsigned short* __restrict__ rsB) {
    __shared__ float sPf[CSEGS * 64], sQf[CSEGS * 64], sPb[CSEGS * 64], sQb[CSEGS * 64];
    __shared__ unsigned s_qi;
    unsigned* pop = ctrl;
    unsigned* flags = ctrl + 1;      // flags[ph * NPLANE + plane], target 27
    const int t = threadIdx.x;

    for (;;) {
        if (t == 0) s_qi = __hip_atomic_fetch_add(pop, 1u, __ATOMIC_RELAXED, __HIP_MEMORY_SCOPE_AGENT);
        __syncthreads();
        unsigned qi = s_qi;
        if (qi >= TOTAL_ITEMS) return;

        if (qi < 3u * PHITEMS) {
            int ph = qi / PHITEMS;
            int rem = qi % PHITEMS;
            int p = rem / IPP, w = rem % IPP;
            int b = p / C, c = p % C;
            if (ph > 0) {
                if (t == 0) {
                    wait_ge(&flags[(ph - 1) * NPLANE + p], 27u);   // own plane, prev phase
                    wait_ge(&flags[b * C], 27u);                   // plane (b,0) phase 0: dcol/drow
                }
                __syncthreads();
            }
            const unsigned short* csin = (ph == 1) ? csA : csB;
            const unsigned short* rsin = (ph == 1) ? rsA : rsB;
            unsigned short* csout = (ph == 1) ? csB : csA;   // ph0 -> A, ph1 -> B, ph2 -> A
            unsigned short* rsout = (ph == 1) ? rsB : rsA;
            if (w < 3) {
                if (ph == 0) col_item<0>(b, c, w, mask, edge, csin, rsin, csout, dcol, drow, sPf, sQf, sPb, sQb, t);
                else         col_item<1>(b, c, w, mask, edge, csin, rsin, csout, dcol, drow, sPf, sQf, sPb, sQb, t);
            } else {
                if (ph == 0) row_item<0>(b, c, w - 3, mask, edge, csin, rsin, rsout, dcol, drow, t);
                else         row_item<1>(b, c, w - 3, mask, edge, csin, rsin, rsout, dcol, drow, t);
            }
            __syncthreads();          // all item writes drained (vmcnt 0) before signal
            if (t == 0)
                __hip_atomic_fetch_add(&flags[ph * NPLANE + p], 1u, __ATOMIC_RELEASE, __HIP_MEMORY_SCOPE_AGENT);
        } else {
            unsigned ci = qi - 3u * PHITEMS;
            int p = ci / COMBPP, chunk = ci % COMBPP;
            if (t == 0) wait_ge(&flags[2 * NPLANE + p], 27u);
            __syncthreads();
            comb_item(p, chunk, csA, rsA, dcol, drow, out, t);
        }
        __syncthreads();              // protect s_qi reuse across loop iterations
    }
}

extern "C" void kernel_launch(void* const* d_in, const int* in_sizes, int n_in,
                              void* d_out, int out_size, void* d_ws, size_t ws_size,
                              hipStream_t stream) {
    const float* mask = (const float*)d_in[0];
    const float* edge = (const float*)d_in[1];
    float* out = (float*)d_out;

    unsigned* ctrl = (unsigned*)d_ws;                       // pop + flags (zeroed per call)
    float* dcol = (float*)(ctrl + NCTRL);                   // [B,H,W] fp32
    float* drow = dcol + (size_t)B * HW;                    // [B,H,W] fp32
    unsigned short* csA = (unsigned short*)(drow + (size_t)B * HW);
    unsigned short* rsA = csA + (size_t)NPLANE * HW;        // bf16 [76,H,W] each
    unsigned short* csB = rsA + (size_t)NPLANE * HW;
    unsigned short* rsB = csB + (size_t)NPLANE * HW;

    k_zero<<<1, NCTRL, 0, stream>>>(ctrl);
    k_pipe<<<NBLOCKS, NTHR, 0, stream>>>(mask, edge, out, ctrl, dcol, drow, csA, rsA, csB, rsB);
}

// Round 14
// 160.510 us; speedup vs baseline: 2.4772x; 2.4772x over previous
//
#include <hip/hip_runtime.h>

#define B 4
#define C 19
#define H 192
#define W 192
#define HW (H * W)
// 40 / ln(2): exp(-40*x) == exp2(-THETA_LOG2E*x)
#define THETA_LOG2E 57.70780163555855f

// k_fused geometry
#define FNT 768
#define FSEGS 8
#define FSR 24        // 8 * 24 = 192
#define FCH 96        // lines per chunk (2 chunks x 96 = 192)
#define PITCH 193     // bf16 pitch: conflict-free both directions

// k_setup roles
#define NSA (B * 36)      // 144 transpose blocks (dmat + dmatT)
#define NSB (B * 3)       // 12 dcol blocks
#define NSC (B * H / 8)   // 96 drow blocks

// bf16 helpers (RNE)
__device__ __forceinline__ unsigned short f2b(float x) {
    unsigned u = __float_as_uint(x);
    u = (u + 0x7FFFu + ((u >> 16) & 1u)) >> 16;
    return (unsigned short)u;
}
__device__ __forceinline__ float b2f(unsigned short h) {
    return __uint_as_float(((unsigned)h) << 16);
}

// ================= setup: dmat, dmatT, dcol, drow in one launch =================
__global__ __launch_bounds__(512) void k_setup(const float* __restrict__ edge,
                                               float* __restrict__ dmat,
                                               float* __restrict__ dmatT,
                                               float* __restrict__ dcol,
                                               float* __restrict__ drow) {
    __shared__ float tile[32][33];
    __shared__ float sP[4][8][64];   // Pf,Qf,Pb,Qb for the dcol role
    const int t = threadIdx.x;
    const int blk = blockIdx.x;

    if (blk < NSA) {
        // ---- role A: dmat = exp2(-theta*relu(edge)) + transposed copy ----
        int tx = blk % 6, ty = (blk / 6) % 6, b = blk / 36;
        if (t < 256) {
            int lx = t % 32, ly = t / 32;
            #pragma unroll
            for (int k = 0; k < 4; ++k) {
                int il = ly + k * 8;
                int I = ty * 32 + il, J = tx * 32 + lx;
                float e = edge[(b * H + I) * W + J];
                float d = exp2f(-THETA_LOG2E * fmaxf(e, 0.f));
                dmat[(b * H + I) * W + J] = d;
                tile[il][lx] = d;
            }
        }
        __syncthreads();
        if (t < 256) {
            int lx = t % 32, ly = t / 32;
            #pragma unroll
            for (int k = 0; k < 4; ++k) {
                int jl = ly + k * 8;
                dmatT[(b * W + tx * 32 + jl) * H + ty * 32 + lx] = tile[lx][jl];
            }
        }
    } else if (blk < NSA + NSB) {
        // ---- role B: dcol = Zu + Su - 1 (unit-f column scan), d from edge on the fly ----
        int bb = blk - NSA;
        int jt = bb % 3, b = bb / 3;
        int jl = t & 63, seg = t >> 6;     // 8 segs x 24 rows
        int j = jt * 64 + jl, i0 = seg * FSR;
        const float* ep = edge + ((size_t)b * H + i0) * W + j;
        float dr[FSR + 1];
        #pragma unroll
        for (int r = 0; r < FSR; ++r) dr[r] = exp2f(-THETA_LOG2E * fmaxf(ep[r * W], 0.f));
        dr[FSR] = (seg < FSEGS - 1) ? exp2f(-THETA_LOG2E * fmaxf(ep[FSR * W], 0.f)) : 0.f;
        float Pf = 1.f, Qf = 0.f, Pb = 1.f, Qb = 0.f;
        #pragma unroll
        for (int r = 0; r < FSR; ++r) { Qf = Qf * dr[r] + 1.f; Pf *= dr[r]; }
        #pragma unroll
        for (int r = FSR - 1; r >= 0; --r) { Qb = Qb * dr[r + 1] + 1.f; Pb *= dr[r + 1]; }
        sP[0][seg][jl] = Pf; sP[1][seg][jl] = Qf;
        sP[2][seg][jl] = Pb; sP[3][seg][jl] = Qb;
        __syncthreads();
        if (seg == 0) {
            float P = sP[0][0][jl], Q = sP[1][0][jl];
            for (int s2 = 1; s2 < FSEGS; ++s2) {
                float Pc = sP[0][s2][jl], Qc = sP[1][s2][jl];
                Q = Q * Pc + Qc; P = P * Pc;
                sP[0][s2][jl] = P; sP[1][s2][jl] = Q;
            }
        } else if (seg == 1) {
            float P = sP[2][FSEGS - 1][jl], Q = sP[3][FSEGS - 1][jl];
            for (int s2 = FSEGS - 2; s2 >= 0; --s2) {
                float Pc = sP[2][s2][jl], Qc = sP[3][s2][jl];
                Q = Q * Pc + Qc; P = P * Pc;
                sP[2][s2][jl] = P; sP[3][s2][jl] = Q;
            }
        }
        __syncthreads();
        float z = (seg > 0) ? sP[1][seg - 1][jl] : 0.f;
        float s = (seg < FSEGS - 1) ? sP[3][seg + 1][jl] : 0.f;
        float zarr[FSR];
        #pragma unroll
        for (int r = 0; r < FSR; ++r) { z = z * dr[r] + 1.f; zarr[r] = z; }
        #pragma unroll
        for (int r = FSR - 1; r >= 0; --r) {
            s = s * dr[r + 1] + 1.f;
            dcol[((size_t)b * H + i0 + r) * W + j] = zarr[r] + s - 1.f;
        }
    } else {
        // ---- role C: drow = Zu + Su - 1 (unit-f row scan), one row per wave ----
        int bb = blk - NSA - NSB;
        int wave = t >> 6, lane = t & 63;
        int gr = bb * 8 + wave;            // 0 .. B*H-1
        int b = gr / H, i = gr % H;
        const int base = (b * H + i) * W;
        const int s0 = 3 * lane;
        float d0 = exp2f(-THETA_LOG2E * fmaxf(edge[base + s0], 0.f));
        float d1 = exp2f(-THETA_LOG2E * fmaxf(edge[base + s0 + 1], 0.f));
        float d2 = exp2f(-THETA_LOG2E * fmaxf(edge[base + s0 + 2], 0.f));
        float d3 = 0.f;
        if (lane < 63) d3 = exp2f(-THETA_LOG2E * fmaxf(edge[base + s0 + 3], 0.f));

        float P = d0 * d1 * d2;
        float Q = d1 * d2 + d2 + 1.f;
        #pragma unroll
        for (int off = 1; off < 64; off <<= 1) {
            float Pp = __shfl_up(P, off);
            float Qp = __shfl_up(Q, off);
            if (lane >= off) { Q = Qp * P + Q; P = Pp * P; }
        }
        float zin = __shfl_up(Q, 1);
        if (lane == 0) zin = 0.f;
        float zA = zin * d0 + 1.f;
        float zB = zA * d1 + 1.f;
        float zC = zB * d2 + 1.f;

        float Pb = d3 * d2 * d1;
        float Qb = d2 * d1 + d1 + 1.f;
        #pragma unroll
        for (int off = 1; off < 64; off <<= 1) {
            float Pp = __shfl_down(Pb, off);
            float Qp = __shfl_down(Qb, off);
            if (lane < 64 - off) { Qb = Qp * Pb + Qb; Pb = Pp * Pb; }
        }
        float sin_ = __shfl_down(Qb, 1);
        if (lane == 63) sin_ = 0.f;
        float sC = sin_ * d3 + 1.f;
        float sB = sC * d2 + 1.f;
        float sA = sB * d1 + 1.f;

        drow[base + s0]     = zA + sA - 1.f;
        drow[base + s0 + 1] = zB + sB - 1.f;
        drow[base + s0 + 2] = zC + sC - 1.f;
    }
}

// ================= fused: 3 iterations for one (b,c) plane, f and cs in bf16 LDS =================
__global__ __launch_bounds__(FNT) void k_fused(const float* __restrict__ mask,
                                               const float* __restrict__ dmat,
                                               const float* __restrict__ dmatT,
                                               const float* __restrict__ dcol,
                                               const float* __restrict__ drow,
                                               float* __restrict__ out) {
    __shared__ unsigned short fpl[H * PITCH];   // 74112 B  f plane (bf16)
    __shared__ unsigned short cpl[H * PITCH];   // 74112 B  colsum plane (bf16)
    __shared__ float2 scrF[FSEGS * FCH];        // 6144 B
    __shared__ float2 scrB[FSEGS * FCH];        // 6144 B   total 160512 <= 163840

    const int t = threadIdx.x;
    const int lc = t % FCH, seg = t / FCH, r0 = seg * FSR;
    const int bc = blockIdx.x, b = bc / C;
    const float* dm  = dmat + (size_t)b * HW;
    const float* dmT = dmatT + (size_t)b * HW;
    const float* dcp = dcol + (size_t)b * HW;
    const float* drp = drow + (size_t)b * HW;
    const float* fin = mask + (size_t)bc * HW;
    float* outp = out + (size_t)bc * HW;

    for (int it = 0; it < 3; ++it) {
        // ---- col phase: cpl = Zc + Sc - f ----
        for (int ch = 0; ch < 2; ++ch) {
            const int j = ch * FCH + lc;
            float dr[FSR + 1], fr[FSR];
            #pragma unroll
            for (int r = 0; r < FSR; ++r) dr[r] = dm[(r0 + r) * W + j];
            dr[FSR] = (seg < FSEGS - 1) ? dm[(r0 + FSR) * W + j] : 0.f;
            if (it == 0) {
                #pragma unroll
                for (int r = 0; r < FSR; ++r) {
                    fr[r] = fin[(r0 + r) * W + j];          // coalesced global
                    fpl[(r0 + r) * PITCH + j] = f2b(fr[r]); // deposit for row phase
                }
            } else {
                #pragma unroll
                for (int r = 0; r < FSR; ++r) fr[r] = b2f(fpl[(r0 + r) * PITCH + j]);
            }
            float Pf = 1.f, Qf = 0.f, Pb = 1.f, Qb = 0.f;
            #pragma unroll
            for (int r = 0; r < FSR; ++r) { Qf = Qf * dr[r] + fr[r]; Pf *= dr[r]; }
            #pragma unroll
            for (int r = FSR - 1; r >= 0; --r) { Qb = Qb * dr[r + 1] + fr[r]; Pb *= dr[r + 1]; }
            __syncthreads();                     // (a) prev scr consumers done
            scrF[seg * FCH + lc] = make_float2(Pf, Qf);
            scrB[seg * FCH + lc] = make_float2(Pb, Qb);
            __syncthreads();                     // (b) scr visible
            float z = 0.f, s = 0.f;
            for (int s2 = 0; s2 < seg; ++s2) { float2 v = scrF[s2 * FCH + lc]; z = z * v.x + v.y; }
            for (int s2 = FSEGS - 1; s2 > seg; --s2) { float2 v = scrB[s2 * FCH + lc]; s = s * v.x + v.y; }
            float zarr[FSR];
            #pragma unroll
            for (int r = 0; r < FSR; ++r) { z = z * dr[r] + fr[r]; zarr[r] = z; }
            #pragma unroll
            for (int r = FSR - 1; r >= 0; --r) {
                s = s * dr[r + 1] + fr[r];
                cpl[(r0 + r) * PITCH + j] = f2b(zarr[r] + s - fr[r]);   // diag once
            }
        }
        __syncthreads();
        // ---- row phase: fpl <- Zr + Sr - 2f (overwrite, row ownership) ----
        for (int ch = 0; ch < 2; ++ch) {
            const int i = ch * FCH + lc;
            float dr[FSR + 1], fr[FSR];
            #pragma unroll
            for (int r = 0; r < FSR; ++r) dr[r] = dmT[(r0 + r) * H + i];  // coalesced
            dr[FSR] = (seg < FSEGS - 1) ? dmT[(r0 + FSR) * H + i] : 0.f;
            #pragma unroll
            for (int r = 0; r < FSR; ++r) fr[r] = b2f(fpl[i * PITCH + r0 + r]);
            float Pf = 1.f, Qf = 0.f, Pb = 1.f, Qb = 0.f;
            #pragma unroll
            for (int r = 0; r < FSR; ++r) { Qf = Qf * dr[r] + fr[r]; Pf *= dr[r]; }
            #pragma unroll
            for (int r = FSR - 1; r >= 0; --r) { Qb = Qb * dr[r + 1] + fr[r]; Pb *= dr[r + 1]; }
            __syncthreads();
            scrF[seg * FCH + lc] = make_float2(Pf, Qf);
            scrB[seg * FCH + lc] = make_float2(Pb, Qb);
            __syncthreads();
            float z = 0.f, s = 0.f;
            for (int s2 = 0; s2 < seg; ++s2) { float2 v = scrF[s2 * FCH + lc]; z = z * v.x + v.y; }
            for (int s2 = FSEGS - 1; s2 > seg; --s2) { float2 v = scrB[s2 * FCH + lc]; s = s * v.x + v.y; }
            float zarr[FSR];
            #pragma unroll
            for (int r = 0; r < FSR; ++r) { z = z * dr[r] + fr[r]; zarr[r] = z; }
            #pragma unroll
            for (int r = FSR - 1; r >= 0; --r) {
                s = s * dr[r + 1] + fr[r];
                fpl[i * PITCH + r0 + r] = f2b(zarr[r] + s - 2.f * fr[r]);
            }
        }
        __syncthreads();
        // ---- combine (col ownership): f' = (cs + rowpart) / (dcol + drow - 1) ----
        for (int ch = 0; ch < 2; ++ch) {
            const int j = ch * FCH + lc;
            #pragma unroll
            for (int r = 0; r < FSR; ++r) {
                const int gi = (r0 + r) * W + j;
                const int li = (r0 + r) * PITCH + j;
                float v = (b2f(cpl[li]) + b2f(fpl[li])) / (dcp[gi] + drp[gi] - 1.f);
                if (it == 2) outp[gi] = v;       // final: straight to global, coalesced
                else         fpl[li] = f2b(v);
            }
        }
        __syncthreads();
    }
}

extern "C" void kernel_launch(void* const* d_in, const int* in_sizes, int n_in,
                              void* d_out, int out_size, void* d_ws, size_t ws_size,
                              hipStream_t stream) {
    const float* mask = (const float*)d_in[0];
    const float* edge = (const float*)d_in[1];
    float* out = (float*)d_out;

    float* dmat  = (float*)d_ws;            // [B,H,W]
    float* dmatT = dmat + (size_t)B * HW;   // [B,W,H]
    float* dcol  = dmatT + (size_t)B * HW;  // [B,H,W]
    float* drow  = dcol + (size_t)B * HW;   // [B,H,W]

    k_setup<<<NSA + NSB + NSC, 512, 0, stream>>>(edge, dmat, dmatT, dcol, drow);
    k_fused<<<B * C, FNT, 0, stream>>>(mask, dmat, dmatT, dcol, drow, out);
}

// Round 15
// 111.727 us; speedup vs baseline: 3.5588x; 1.4366x over previous
//
#include <hip/hip_runtime.h>

#define B 4
#define C 19
#define H 192
#define W 192
#define HW (H * W)
// 40 / ln(2): exp(-40*x) == exp2(-THETA_LOG2E*x)
#define THETA_LOG2E 57.70780163555855f

// k_fused geometry: 512 threads = 8 waves (allocator gives <=512-thr blocks ~88+ VGPRs; 768/1024 pin at 84/64)
#define FNT 512
#define FSEGS 8
#define FSR 24        // 8 * 24 = 192 rows per scan line
#define FCH 64        // lines per chunk (3 chunks x 64 = 192)
#define PITCH 193     // bf16 pitch: <=2-way bank aliasing in both directions (free per m136)

// k_setup roles
#define NSA (B * 36)      // 144 transpose blocks (dmat + dmatT)
#define NSB (B * 3)       // 12 dcol blocks
#define NSC (B * H / 8)   // 96 drow blocks

// bf16 helpers (RNE)
__device__ __forceinline__ unsigned short f2b(float x) {
    unsigned u = __float_as_uint(x);
    u = (u + 0x7FFFu + ((u >> 16) & 1u)) >> 16;
    return (unsigned short)u;
}
__device__ __forceinline__ float b2f(unsigned short h) {
    return __uint_as_float(((unsigned)h) << 16);
}

// ================= setup: dmat, dmatT, dcol, drow in one launch =================
__global__ __launch_bounds__(512) void k_setup(const float* __restrict__ edge,
                                               float* __restrict__ dmat,
                                               float* __restrict__ dmatT,
                                               float* __restrict__ dcol,
                                               float* __restrict__ drow) {
    __shared__ float tile[32][33];
    __shared__ float sP[4][8][64];   // Pf,Qf,Pb,Qb for the dcol role
    const int t = threadIdx.x;
    const int blk = blockIdx.x;

    if (blk < NSA) {
        // ---- role A: dmat = exp2(-theta*relu(edge)) + transposed copy ----
        int tx = blk % 6, ty = (blk / 6) % 6, b = blk / 36;
        if (t < 256) {
            int lx = t % 32, ly = t / 32;
            #pragma unroll
            for (int k = 0; k < 4; ++k) {
                int il = ly + k * 8;
                int I = ty * 32 + il, J = tx * 32 + lx;
                float e = edge[(b * H + I) * W + J];
                float d = exp2f(-THETA_LOG2E * fmaxf(e, 0.f));
                dmat[(b * H + I) * W + J] = d;
                tile[il][lx] = d;
            }
        }
        __syncthreads();
        if (t < 256) {
            int lx = t % 32, ly = t / 32;
            #pragma unroll
            for (int k = 0; k < 4; ++k) {
                int jl = ly + k * 8;
                dmatT[(b * W + tx * 32 + jl) * H + ty * 32 + lx] = tile[lx][jl];
            }
        }
    } else if (blk < NSA + NSB) {
        // ---- role B: dcol = Zu + Su - 1 (unit-f column scan), d from edge on the fly ----
        int bb = blk - NSA;
        int jt = bb % 3, b = bb / 3;
        int jl = t & 63, seg = t >> 6;     // 8 segs x 24 rows
        int j = jt * 64 + jl, i0 = seg * FSR;
        const float* ep = edge + ((size_t)b * H + i0) * W + j;
        float dr[FSR + 1];
        #pragma unroll
        for (int r = 0; r < FSR; ++r) dr[r] = exp2f(-THETA_LOG2E * fmaxf(ep[r * W], 0.f));
        dr[FSR] = (seg < FSEGS - 1) ? exp2f(-THETA_LOG2E * fmaxf(ep[FSR * W], 0.f)) : 0.f;
        float Pf = 1.f, Qf = 0.f, Pb = 1.f, Qb = 0.f;
        #pragma unroll
        for (int r = 0; r < FSR; ++r) { Qf = Qf * dr[r] + 1.f; Pf *= dr[r]; }
        #pragma unroll
        for (int r = FSR - 1; r >= 0; --r) { Qb = Qb * dr[r + 1] + 1.f; Pb *= dr[r + 1]; }
        sP[0][seg][jl] = Pf; sP[1][seg][jl] = Qf;
        sP[2][seg][jl] = Pb; sP[3][seg][jl] = Qb;
        __syncthreads();
        if (seg == 0) {
            float P = sP[0][0][jl], Q = sP[1][0][jl];
            for (int s2 = 1; s2 < FSEGS; ++s2) {
                float Pc = sP[0][s2][jl], Qc = sP[1][s2][jl];
                Q = Q * Pc + Qc; P = P * Pc;
                sP[0][s2][jl] = P; sP[1][s2][jl] = Q;
            }
        } else if (seg == 1) {
            float P = sP[2][FSEGS - 1][jl], Q = sP[3][FSEGS - 1][jl];
            for (int s2 = FSEGS - 2; s2 >= 0; --s2) {
                float Pc = sP[2][s2][jl], Qc = sP[3][s2][jl];
                Q = Q * Pc + Qc; P = P * Pc;
                sP[2][s2][jl] = P; sP[3][s2][jl] = Q;
            }
        }
        __syncthreads();
        float z = (seg > 0) ? sP[1][seg - 1][jl] : 0.f;
        float s = (seg < FSEGS - 1) ? sP[3][seg + 1][jl] : 0.f;
        float zarr[FSR];
        #pragma unroll
        for (int r = 0; r < FSR; ++r) { z = z * dr[r] + 1.f; zarr[r] = z; }
        #pragma unroll
        for (int r = FSR - 1; r >= 0; --r) {
            s = s * dr[r + 1] + 1.f;
            dcol[((size_t)b * H + i0 + r) * W + j] = zarr[r] + s - 1.f;
        }
    } else {
        // ---- role C: drow = Zu + Su - 1 (unit-f row scan), one row per wave ----
        int bb = blk - NSA - NSB;
        int wave = t >> 6, lane = t & 63;
        int gr = bb * 8 + wave;            // 0 .. B*H-1
        int b = gr / H, i = gr % H;
        const int base = (b * H + i) * W;
        const int s0 = 3 * lane;
        float d0 = exp2f(-THETA_LOG2E * fmaxf(edge[base + s0], 0.f));
        float d1 = exp2f(-THETA_LOG2E * fmaxf(edge[base + s0 + 1], 0.f));
        float d2 = exp2f(-THETA_LOG2E * fmaxf(edge[base + s0 + 2], 0.f));
        float d3 = 0.f;
        if (lane < 63) d3 = exp2f(-THETA_LOG2E * fmaxf(edge[base + s0 + 3], 0.f));

        float P = d0 * d1 * d2;
        float Q = d1 * d2 + d2 + 1.f;
        #pragma unroll
        for (int off = 1; off < 64; off <<= 1) {
            float Pp = __shfl_up(P, off);
            float Qp = __shfl_up(Q, off);
            if (lane >= off) { Q = Qp * P + Q; P = Pp * P; }
        }
        float zin = __shfl_up(Q, 1);
        if (lane == 0) zin = 0.f;
        float zA = zin * d0 + 1.f;
        float zB = zA * d1 + 1.f;
        float zC = zB * d2 + 1.f;

        float Pb = d3 * d2 * d1;
        float Qb = d2 * d1 + d1 + 1.f;
        #pragma unroll
        for (int off = 1; off < 64; off <<= 1) {
            float Pp = __shfl_down(Pb, off);
            float Qp = __shfl_down(Qb, off);
            if (lane < 64 - off) { Qb = Qp * Pb + Qb; Pb = Pp * Pb; }
        }
        float sin_ = __shfl_down(Qb, 1);
        if (lane == 63) sin_ = 0.f;
        float sC = sin_ * d3 + 1.f;
        float sB = sC * d2 + 1.f;
        float sA = sB * d1 + 1.f;

        drow[base + s0]     = zA + sA - 1.f;
        drow[base + s0 + 1] = zB + sB - 1.f;
        drow[base + s0 + 2] = zC + sC - 1.f;
    }
}

// ================= fused: 3 iterations for one (b,c) plane, f and cs in bf16 LDS =================
__global__ __launch_bounds__(FNT, 2) void k_fused(const float* __restrict__ mask,
                                                  const float* __restrict__ dmat,
                                                  const float* __restrict__ dmatT,
                                                  const float* __restrict__ dcol,
                                                  const float* __restrict__ drow,
                                                  float* __restrict__ out) {
    __shared__ unsigned short fpl[H * PITCH];   // 74112 B  f plane (bf16)
    __shared__ unsigned short cpl[H * PITCH];   // 74112 B  colsum plane (bf16)
    __shared__ float2 scrF[FSEGS * FCH];        // 4096 B
    __shared__ float2 scrB[FSEGS * FCH];        // 4096 B   total 156416 <= 163840

    const int t = threadIdx.x;
    const int lane = t & 63, seg = t >> 6, r0 = seg * FSR;
    const int bc = blockIdx.x, b = bc / C;
    const float* dm  = dmat + (size_t)b * HW;
    const float* dmT = dmatT + (size_t)b * HW;
    const float* dcp = dcol + (size_t)b * HW;
    const float* drp = drow + (size_t)b * HW;
    const float* fin = mask + (size_t)bc * HW;
    float* outp = out + (size_t)bc * HW;

    for (int it = 0; it < 3; ++it) {
        // ---- col phase: cpl = Zc + Sc - f ----
        for (int ch = 0; ch < 3; ++ch) {
            const int j = ch * FCH + lane;
            float dr[FSR + 1], fr[FSR];
            #pragma unroll
            for (int r = 0; r < FSR; ++r) dr[r] = dm[(r0 + r) * W + j];
            dr[FSR] = (seg < FSEGS - 1) ? dm[(r0 + FSR) * W + j] : 0.f;
            if (it == 0) {
                #pragma unroll
                for (int r = 0; r < FSR; ++r) {
                    fr[r] = fin[(r0 + r) * W + j];          // coalesced global
                    fpl[(r0 + r) * PITCH + j] = f2b(fr[r]); // deposit for row phase
                }
            } else {
                #pragma unroll
                for (int r = 0; r < FSR; ++r) fr[r] = b2f(fpl[(r0 + r) * PITCH + j]);
            }
            float Pf = 1.f, Qf = 0.f, Pb = 1.f, Qb = 0.f;
            #pragma unroll
            for (int r = 0; r < FSR; ++r) { Qf = Qf * dr[r] + fr[r]; Pf *= dr[r]; }
            #pragma unroll
            for (int r = FSR - 1; r >= 0; --r) { Qb = Qb * dr[r + 1] + fr[r]; Pb *= dr[r + 1]; }
            __syncthreads();                     // (a) prev scr consumers done
            scrF[seg * FCH + lane] = make_float2(Pf, Qf);
            scrB[seg * FCH + lane] = make_float2(Pb, Qb);
            __syncthreads();                     // (b) scr visible
            float z = 0.f, s = 0.f;
            for (int s2 = 0; s2 < seg; ++s2) { float2 v = scrF[s2 * FCH + lane]; z = z * v.x + v.y; }
            for (int s2 = FSEGS - 1; s2 > seg; --s2) { float2 v = scrB[s2 * FCH + lane]; s = s * v.x + v.y; }
            float zarr[FSR];
            #pragma unroll
            for (int r = 0; r < FSR; ++r) { z = z * dr[r] + fr[r]; zarr[r] = z; }
            #pragma unroll
            for (int r = FSR - 1; r >= 0; --r) {
                s = s * dr[r + 1] + fr[r];
                cpl[(r0 + r) * PITCH + j] = f2b(zarr[r] + s - fr[r]);   // diag once
            }
        }
        __syncthreads();
        // ---- row phase: fpl <- Zr + Sr - 2f (overwrite, row ownership) ----
        for (int ch = 0; ch < 3; ++ch) {
            const int i = ch * FCH + lane;
            float dr[FSR + 1], fr[FSR];
            #pragma unroll
            for (int r = 0; r < FSR; ++r) dr[r] = dmT[(r0 + r) * H + i];  // coalesced
            dr[FSR] = (seg < FSEGS - 1) ? dmT[(r0 + FSR) * H + i] : 0.f;
            #pragma unroll
            for (int r = 0; r < FSR; ++r) fr[r] = b2f(fpl[i * PITCH + r0 + r]);
            float Pf = 1.f, Qf = 0.f, Pb = 1.f, Qb = 0.f;
            #pragma unroll
            for (int r = 0; r < FSR; ++r) { Qf = Qf * dr[r] + fr[r]; Pf *= dr[r]; }
            #pragma unroll
            for (int r = FSR - 1; r >= 0; --r) { Qb = Qb * dr[r + 1] + fr[r]; Pb *= dr[r + 1]; }
            __syncthreads();
            scrF[seg * FCH + lane] = make_float2(Pf, Qf);
            scrB[seg * FCH + lane] = make_float2(Pb, Qb);
            __syncthreads();
            float z = 0.f, s = 0.f;
            for (int s2 = 0; s2 < seg; ++s2) { float2 v = scrF[s2 * FCH + lane]; z = z * v.x + v.y; }
            for (int s2 = FSEGS - 1; s2 > seg; --s2) { float2 v = scrB[s2 * FCH + lane]; s = s * v.x + v.y; }
            float zarr[FSR];
            #pragma unroll
            for (int r = 0; r < FSR; ++r) { z = z * dr[r] + fr[r]; zarr[r] = z; }
            #pragma unroll
            for (int r = FSR - 1; r >= 0; --r) {
                s = s * dr[r + 1] + fr[r];
                fpl[i * PITCH + r0 + r] = f2b(zarr[r] + s - 2.f * fr[r]);
            }
        }
        __syncthreads();
        // ---- combine (col ownership): f' = (cs + rowpart) / (dcol + drow - 1) ----
        for (int ch = 0; ch < 3; ++ch) {
            const int j = ch * FCH + lane;
            #pragma unroll
            for (int r = 0; r < FSR; ++r) {
                const int gi = (r0 + r) * W + j;
                const int li = (r0 + r) * PITCH + j;
                float v = (b2f(cpl[li]) + b2f(fpl[li])) / (dcp[gi] + drp[gi] - 1.f);
                if (it == 2) outp[gi] = v;       // final: straight to global, coalesced
                else         fpl[li] = f2b(v);
            }
        }
        __syncthreads();
    }
}

extern "C" void kernel_launch(void* const* d_in, const int* in_sizes, int n_in,
                              void* d_out, int out_size, void* d_ws, size_t ws_size,
                              hipStream_t stream) {
    const float* mask = (const float*)d_in[0];
    const float* edge = (const float*)d_in[1];
    float* out = (float*)d_out;

    float* dmat  = (float*)d_ws;            // [B,H,W]
    float* dmatT = dmat + (size_t)B * HW;   // [B,W,H]
    float* dcol  = dmatT + (size_t)B * HW;  // [B,H,W]
    float* drow  = dcol + (size_t)B * HW;   // [B,H,W]

    k_setup<<<NSA + NSB + NSC, 512, 0, stream>>>(edge, dmat, dmatT, dcol, drow);
    k_fused<<<B * C, FNT, 0, stream>>>(mask, dmat, dmatT, dcol, drow, out);
}

// Round 16
// 60.932 us; speedup vs baseline: 6.5255x; 1.8336x over previous
//
#include <hip/hip_runtime.h>

#define B 4
#define C 19
#define H 192
#define W 192
#define HW (H * W)
#define NP (B * C)
// 40 / ln(2): exp(-40*x) == exp2(-THETA_LOG2E*x)
#define THETA_LOG2E 57.70780163555855f

#define NCOL 228          // col-role blocks (NP * 3)
#define NROW 912          // row-role blocks (8 waves x 2 rows each -> 16 rows/block)
#define RSTRIDE 7296      // NROW * 8

// k_first extra roles
#define C1_BEG (NCOL + NROW)        // 1140: dT transpose, 144 blocks
#define C2_BEG (C1_BEG + 144)       // 1284: dcol (N+T), 12 blocks
#define C3_BEG (C2_BEG + 12)        // 1296: drow (N+T), 12 blocks
#define NFIRST (C3_BEG + 12)        // 1308

// bf16 helpers (RNE)
__device__ __forceinline__ unsigned short f2b(float x) {
    unsigned u = __float_as_uint(x);
    u = (u + 0x7FFFu + ((u >> 16) & 1u)) >> 16;
    return (unsigned short)u;
}
__device__ __forceinline__ float b2f(unsigned short h) {
    return __uint_as_float(((unsigned)h) << 16);
}

// in-wave bidirectional first-order scan over 192 elems (3/lane), proven R11 math.
// d3 MUST be 0 for lane 63.  Z[s]=d[s]Z[s-1]+f[s];  S[s]=d[s+1]S[s+1]+f[s].
__device__ __forceinline__ void ks_scan(int lane, float f0, float f1, float f2v,
                                        float d0, float d1, float d2, float d3,
                                        float& zA, float& zB, float& zC,
                                        float& sA, float& sB, float& sC) {
    float P = d0 * d1 * d2;
    float Q = (f0 * d1 + f1) * d2 + f2v;
    #pragma unroll
    for (int off = 1; off < 64; off <<= 1) {
        float Pp = __shfl_up(P, off), Qp = __shfl_up(Q, off);
        if (lane >= off) { Q = Qp * P + Q; P = Pp * P; }
    }
    float zin = __shfl_up(Q, 1);
    if (lane == 0) zin = 0.f;
    zA = zin * d0 + f0; zB = zA * d1 + f1; zC = zB * d2 + f2v;
    float Pb = d3 * d2 * d1;
    float Qb = (f2v * d2 + f1) * d1 + f0;
    #pragma unroll
    for (int off = 1; off < 64; off <<= 1) {
        float Pp = __shfl_down(Pb, off), Qp = __shfl_down(Qb, off);
        if (lane < 64 - off) { Qb = Qp * Pb + Qb; Pb = Pp * Pb; }
    }
    float sin_ = __shfl_down(Qb, 1);
    if (lane == 63) sin_ = 0.f;
    sC = sin_ * d3 + f2v; sB = sC * d2 + f1; sA = sB * d1 + f0;
}

// ================= launch 1: cs0, rs0 + all edge-derived constants =================
__global__ __launch_bounds__(512) void k_first(const float* __restrict__ mask,
                                               const float* __restrict__ edge,
                                               unsigned short* __restrict__ csA,
                                               unsigned short* __restrict__ rsA,
                                               float* __restrict__ dT,
                                               float* __restrict__ dcolN,
                                               float* __restrict__ drowN,
                                               float* __restrict__ dcolT,
                                               float* __restrict__ drowT) {
    __shared__ float tf[192 * 65];          // 49.9 KB (f32 tile / stage)
    __shared__ unsigned short tu[192 * 66]; // 25.3 KB (bf16 tile)
    const int t = threadIdx.x, lane = t & 63, wave = t >> 6;
    const int bx = blockIdx.x;

    if (bx < NCOL) {
        // ---- col role MODE0: cs0 = colscan(mask) for [plane p, 64 cols] ----
        int jt = bx % 3, p = bx / 3, b = p / C;
        #pragma unroll
        for (int k = 0; k < 12; ++k) {
            int e = t + k * 512; int i = e >> 5, jp = e & 31;
            float2 mv = *(const float2*)&mask[(size_t)p * HW + i * W + jt * 64 + 2 * jp];
            ((unsigned*)tu)[33 * i + jp] = (unsigned)f2b(mv.x) | ((unsigned)f2b(mv.y) << 16);
            float2 ev = *(const float2*)&edge[(size_t)b * HW + i * W + jt * 64 + 2 * jp];
            tf[65 * i + 2 * jp]     = exp2f(-THETA_LOG2E * fmaxf(ev.x, 0.f));
            tf[65 * i + 2 * jp + 1] = exp2f(-THETA_LOG2E * fmaxf(ev.y, 0.f));
        }
        __syncthreads();
        #pragma unroll
        for (int q = 0; q < 8; ++q) {
            int jl = wave * 8 + q;
            int r0 = 3 * lane;
            float f0 = b2f(tu[r0 * 66 + jl]), f1 = b2f(tu[(r0 + 1) * 66 + jl]), f2v = b2f(tu[(r0 + 2) * 66 + jl]);
            float d0 = tf[r0 * 65 + jl], d1 = tf[(r0 + 1) * 65 + jl], d2 = tf[(r0 + 2) * 65 + jl];
            float d3 = (lane < 63) ? tf[(r0 + 3) * 65 + jl] : 0.f;
            float zA, zB, zC, sA, sB, sC;
            ks_scan(lane, f0, f1, f2v, d0, d1, d2, d3, zA, zB, zC, sA, sB, sC);
            tu[r0 * 66 + jl]       = f2b(zA + sA - f0);    // diag counted once
            tu[(r0 + 1) * 66 + jl] = f2b(zB + sB - f1);
            tu[(r0 + 2) * 66 + jl] = f2b(zC + sC - f2v);
        }
        __syncthreads();
        #pragma unroll
        for (int k = 0; k < 12; ++k) {
            int e = t + k * 512; int i = e >> 5, jp = e & 31;
            *(unsigned*)&csA[(size_t)p * HW + i * W + jt * 64 + 2 * jp] = ((unsigned*)tu)[33 * i + jp];
        }
    } else if (bx < NCOL + NROW) {
        // ---- row role MODE0: rs0 = rowscan(mask) - 2f, 2 rows per wave ----
        int rblk = bx - NCOL;
        #pragma unroll
        for (int k = 0; k < 2; ++k) {
            int rr = rblk * 8 + wave + k * RSTRIDE;
            int i = rr % H, c = (rr / H) % C, b = rr / (H * C);
            size_t rb = (size_t)(b * C + c) * HW + (size_t)i * W;
            size_t db = (size_t)b * HW + (size_t)i * W;
            int s0 = 3 * lane;
            float d0 = exp2f(-THETA_LOG2E * fmaxf(edge[db + s0], 0.f));
            float d1 = exp2f(-THETA_LOG2E * fmaxf(edge[db + s0 + 1], 0.f));
            float d2 = exp2f(-THETA_LOG2E * fmaxf(edge[db + s0 + 2], 0.f));
            float d3 = 0.f;
            if (lane < 63) d3 = exp2f(-THETA_LOG2E * fmaxf(edge[db + s0 + 3], 0.f));
            float f0 = mask[rb + s0], f1 = mask[rb + s0 + 1], f2v = mask[rb + s0 + 2];
            float zA, zB, zC, sA, sB, sC;
            ks_scan(lane, f0, f1, f2v, d0, d1, d2, d3, zA, zB, zC, sA, sB, sC);
            rsA[rb + s0]     = f2b(zA + sA - 2.f * f0);
            rsA[rb + s0 + 1] = f2b(zB + sB - 2.f * f1);
            rsA[rb + s0 + 2] = f2b(zC + sC - 2.f * f2v);
        }
    } else if (bx < C2_BEG) {
        // ---- role c1: dT[b][j][i] = exp2(-theta*relu(edge[i][j])) (transpose) ----
        int blk = bx - C1_BEG;
        int tx = blk % 6, ty = (blk / 6) % 6, b = blk / 36;
        if (t < 256) {
            int lx = t % 32, ly = t / 32;
            #pragma unroll
            for (int k = 0; k < 4; ++k) {
                int il = ly + k * 8;
                int I = ty * 32 + il, J = tx * 32 + lx;
                float e = edge[(b * H + I) * W + J];
                tf[il * 33 + lx] = exp2f(-THETA_LOG2E * fmaxf(e, 0.f));
            }
        }
        __syncthreads();
        if (t < 256) {
            int lx = t % 32, ly = t / 32;
            #pragma unroll
            for (int k = 0; k < 4; ++k) {
                int jl = ly + k * 8;
                dT[((size_t)b * W + tx * 32 + jl) * H + ty * 32 + lx] = tf[lx * 33 + jl];
            }
        }
    } else if (bx < C3_BEG) {
        // ---- role c2: dcolN + dcolT (unit-f column scans via KS) ----
        int bb = bx - C2_BEG; int jt = bb % 3, b = bb / 3;
        #pragma unroll
        for (int k = 0; k < 12; ++k) {
            int e = t + k * 512; int i = e >> 5, jp = e & 31;
            float2 ev = *(const float2*)&edge[(size_t)b * HW + i * W + jt * 64 + 2 * jp];
            tf[65 * i + 2 * jp]     = exp2f(-THETA_LOG2E * fmaxf(ev.x, 0.f));
            tf[65 * i + 2 * jp + 1] = exp2f(-THETA_LOG2E * fmaxf(ev.y, 0.f));
        }
        __syncthreads();
        #pragma unroll
        for (int q = 0; q < 8; ++q) {
            int jl = wave * 8 + q;
            int j = jt * 64 + jl;
            int r0 = 3 * lane;
            float d0 = tf[r0 * 65 + jl], d1 = tf[(r0 + 1) * 65 + jl], d2 = tf[(r0 + 2) * 65 + jl];
            float d3 = (lane < 63) ? tf[(r0 + 3) * 65 + jl] : 0.f;
            float zA, zB, zC, sA, sB, sC;
            ks_scan(lane, 1.f, 1.f, 1.f, d0, d1, d2, d3, zA, zB, zC, sA, sB, sC);
            float uA = zA + sA - 1.f, uB = zB + sB - 1.f, uC = zC + sC - 1.f;
            size_t tb = ((size_t)b * W + j) * H + r0;
            dcolT[tb] = uA; dcolT[tb + 1] = uB; dcolT[tb + 2] = uC;
            tf[r0 * 65 + jl] = uA; tf[(r0 + 1) * 65 + jl] = uB; tf[(r0 + 2) * 65 + jl] = uC;
        }
        __syncthreads();
        #pragma unroll
        for (int k = 0; k < 24; ++k) {
            int e = t + k * 512; int i = e >> 6, jl = e & 63;
            dcolN[(size_t)b * HW + i * W + jt * 64 + jl] = tf[65 * i + jl];
        }
    } else {
        // ---- role c3: drowN + drowT (unit-f row scans via KS), 64 rows/block ----
        int bb = bx - C3_BEG; int b = bb / 3, i0 = (bb % 3) * 64;
        #pragma unroll
        for (int k = 0; k < 8; ++k) {
            int il = wave * 8 + k;
            int i = i0 + il;
            size_t db = (size_t)b * HW + (size_t)i * W;
            int s0 = 3 * lane;
            float d0 = exp2f(-THETA_LOG2E * fmaxf(edge[db + s0], 0.f));
            float d1 = exp2f(-THETA_LOG2E * fmaxf(edge[db + s0 + 1], 0.f));
            float d2 = exp2f(-THETA_LOG2E * fmaxf(edge[db + s0 + 2], 0.f));
            float d3 = 0.f;
            if (lane < 63) d3 = exp2f(-THETA_LOG2E * fmaxf(edge[db + s0 + 3], 0.f));
            float zA, zB, zC, sA, sB, sC;
            ks_scan(lane, 1.f, 1.f, 1.f, d0, d1, d2, d3, zA, zB, zC, sA, sB, sC);
            float uA = zA + sA - 1.f, uB = zB + sB - 1.f, uC = zC + sC - 1.f;
            drowN[db + s0] = uA; drowN[db + s0 + 1] = uB; drowN[db + s0 + 2] = uC;
            tf[il * 193 + s0] = uA; tf[il * 193 + s0 + 1] = uB; tf[il * 193 + s0 + 2] = uC;
        }
        __syncthreads();
        #pragma unroll
        for (int k = 0; k < 24; ++k) {
            int e = t + k * 512; int j = e >> 6, il = e & 63;   // 64*192 elems
            drowT[((size_t)b * W + j) * H + i0 + il] = tf[il * 193 + j];
        }
    }
}

// ================= iteration launch (MODE1): fold + scans, both roles =================
__global__ __launch_bounds__(512) void k_iter2(const unsigned short* __restrict__ csin,
                                               const unsigned short* __restrict__ rsin,
                                               unsigned short* __restrict__ csout,
                                               unsigned short* __restrict__ rsout,
                                               const float* __restrict__ edge,
                                               const float* __restrict__ dT,
                                               const float* __restrict__ dcolN,
                                               const float* __restrict__ drowN,
                                               const float* __restrict__ dcolT,
                                               const float* __restrict__ drowT) {
    __shared__ unsigned short tcs[192 * 66], trs[192 * 66];   // 50.7 KB
    const int t = threadIdx.x, lane = t & 63, wave = t >> 6;
    const int bx = blockIdx.x;

    if (bx < NCOL) {
        // ---- col role: cs_k = colscan(f), f = (cs+rs)/(dcol+drow-1) ----
        int jt = bx % 3, p = bx / 3, b = p / C;
        #pragma unroll
        for (int k = 0; k < 12; ++k) {
            int e = t + k * 512; int i = e >> 5, jp = e & 31;
            size_t g = (size_t)p * HW + i * W + jt * 64 + 2 * jp;
            ((unsigned*)tcs)[33 * i + jp] = *(const unsigned*)&csin[g];
            ((unsigned*)trs)[33 * i + jp] = *(const unsigned*)&rsin[g];
        }
        __syncthreads();
        #pragma unroll
        for (int q = 0; q < 8; ++q) {
            int jl = wave * 8 + q;
            int j = jt * 64 + jl;
            int r0 = 3 * lane;
            size_t tb = ((size_t)b * W + j) * H + r0;
            float rd0 = 1.f / (dcolT[tb]     + drowT[tb]     - 1.f);
            float rd1 = 1.f / (dcolT[tb + 1] + drowT[tb + 1] - 1.f);
            float rd2 = 1.f / (dcolT[tb + 2] + drowT[tb + 2] - 1.f);
            float f0 = (b2f(tcs[r0 * 66 + jl])       + b2f(trs[r0 * 66 + jl]))       * rd0;
            float f1 = (b2f(tcs[(r0 + 1) * 66 + jl]) + b2f(trs[(r0 + 1) * 66 + jl])) * rd1;
            float f2v = (b2f(tcs[(r0 + 2) * 66 + jl]) + b2f(trs[(r0 + 2) * 66 + jl])) * rd2;
            float d0 = dT[tb], d1 = dT[tb + 1], d2 = dT[tb + 2];
            float d3 = (lane < 63) ? dT[tb + 3] : 0.f;
            float zA, zB, zC, sA, sB, sC;
            ks_scan(lane, f0, f1, f2v, d0, d1, d2, d3, zA, zB, zC, sA, sB, sC);
            tcs[r0 * 66 + jl]       = f2b(zA + sA - f0);
            tcs[(r0 + 1) * 66 + jl] = f2b(zB + sB - f1);
            tcs[(r0 + 2) * 66 + jl] = f2b(zC + sC - f2v);
        }
        __syncthreads();
        #pragma unroll
        for (int k = 0; k < 12; ++k) {
            int e = t + k * 512; int i = e >> 5, jp = e & 31;
            *(unsigned*)&csout[(size_t)p * HW + i * W + jt * 64 + 2 * jp] = ((unsigned*)tcs)[33 * i + jp];
        }
    } else {
        // ---- row role: rs_k = rowscan(f) - 2f ----
        int rblk = bx - NCOL;
        #pragma unroll
        for (int k = 0; k < 2; ++k) {
            int rr = rblk * 8 + wave + k * RSTRIDE;
            int i = rr % H, c = (rr / H) % C, b = rr / (H * C);
            size_t rb = (size_t)(b * C + c) * HW + (size_t)i * W;
            size_t db = (size_t)b * HW + (size_t)i * W;
            int s0 = 3 * lane;
            float d0 = exp2f(-THETA_LOG2E * fmaxf(edge[db + s0], 0.f));
            float d1 = exp2f(-THETA_LOG2E * fmaxf(edge[db + s0 + 1], 0.f));
            float d2 = exp2f(-THETA_LOG2E * fmaxf(edge[db + s0 + 2], 0.f));
            float d3 = 0.f;
            if (lane < 63) d3 = exp2f(-THETA_LOG2E * fmaxf(edge[db + s0 + 3], 0.f));
            float rd0 = 1.f / (dcolN[db + s0]     + drowN[db + s0]     - 1.f);
            float rd1 = 1.f / (dcolN[db + s0 + 1] + drowN[db + s0 + 1] - 1.f);
            float rd2 = 1.f / (dcolN[db + s0 + 2] + drowN[db + s0 + 2] - 1.f);
            float f0 = (b2f(csin[rb + s0])     + b2f(rsin[rb + s0]))     * rd0;
            float f1 = (b2f(csin[rb + s0 + 1]) + b2f(rsin[rb + s0 + 1])) * rd1;
            float f2v = (b2f(csin[rb + s0 + 2]) + b2f(rsin[rb + s0 + 2])) * rd2;
            float zA, zB, zC, sA, sB, sC;
            ks_scan(lane, f0, f1, f2v, d0, d1, d2, d3, zA, zB, zC, sA, sB, sC);
            rsout[rb + s0]     = f2b(zA + sA - 2.f * f0);
            rsout[rb + s0 + 1] = f2b(zB + sB - 2.f * f1);
            rsout[rb + s0 + 2] = f2b(zC + sC - 2.f * f2v);
        }
    }
}

// ================= final combine: out = (cs + rs) / (dcol + drow - 1) =================
__global__ __launch_bounds__(256) void k_comb(const unsigned short* __restrict__ cs,
                                              const unsigned short* __restrict__ rs,
                                              const float* __restrict__ dcolN,
                                              const float* __restrict__ drowN,
                                              float* __restrict__ out) {
    int idx4 = (blockIdx.x * 256 + threadIdx.x) * 4;
    int p = idx4 / HW;
    int rem = idx4 - p * HW;
    int b = p / C;
    size_t db = (size_t)b * HW + rem;
    uint2 csu = *(const uint2*)(cs + idx4);
    uint2 rsu = *(const uint2*)(rs + idx4);
    float4 dc = *(const float4*)(dcolN + db);
    float4 dw = *(const float4*)(drowN + db);
    float4 o;
    o.x = (b2f((unsigned short)(csu.x & 0xffff)) + b2f((unsigned short)(rsu.x & 0xffff))) / (dc.x + dw.x - 1.f);
    o.y = (b2f((unsigned short)(csu.x >> 16))    + b2f((unsigned short)(rsu.x >> 16)))    / (dc.y + dw.y - 1.f);
    o.z = (b2f((unsigned short)(csu.y & 0xffff)) + b2f((unsigned short)(rsu.y & 0xffff))) / (dc.z + dw.z - 1.f);
    o.w = (b2f((unsigned short)(csu.y >> 16))    + b2f((unsigned short)(rsu.y >> 16)))    / (dc.w + dw.w - 1.f);
    *(float4*)(out + idx4) = o;
}

extern "C" void kernel_launch(void* const* d_in, const int* in_sizes, int n_in,
                              void* d_out, int out_size, void* d_ws, size_t ws_size,
                              hipStream_t stream) {
    const float* mask = (const float*)d_in[0];
    const float* edge = (const float*)d_in[1];
    float* out = (float*)d_out;

    float* dT    = (float*)d_ws;                    // [B,W,H]
    float* dcolN = dT + (size_t)B * HW;             // [B,H,W]
    float* drowN = dcolN + (size_t)B * HW;          // [B,H,W]
    float* dcolT = drowN + (size_t)B * HW;          // [B,W,H]
    float* drowT = dcolT + (size_t)B * HW;          // [B,W,H]
    unsigned short* csA = (unsigned short*)(drowT + (size_t)B * HW);
    unsigned short* rsA = csA + (size_t)NP * HW;    // bf16 [NP,H,W] each
    unsigned short* csB = rsA + (size_t)NP * HW;
    unsigned short* rsB = csB + (size_t)NP * HW;

    // L1: cs0, rs0 + dT/dcol/drow (N and T)
    k_first<<<NFIRST, 512, 0, stream>>>(mask, edge, csA, rsA, dT, dcolN, drowN, dcolT, drowT);
    // L2: fold A -> B
    k_iter2<<<NCOL + NROW, 512, 0, stream>>>(csA, rsA, csB, rsB, edge, dT, dcolN, drowN, dcolT, drowT);
    // L3: fold B -> A
    k_iter2<<<NCOL + NROW, 512, 0, stream>>>(csB, rsB, csA, rsA, edge, dT, dcolN, drowN, dcolT, drowT);
    // final combine
    k_comb<<<(NP * HW) / (4 * 256), 256, 0, stream>>>(csA, rsA, dcolN, drowN, out);
}